// Round 1
// baseline (5705.109 us; speedup 1.0000x reference)
//
#include <hip/hip_runtime.h>
#include <cmath>

// Problem constants (B=8, T=4096, D=1024, DC=512, E=64)
#define N_TOK   32768
#define D0      1024
#define DC      512
#define DIN     1536      // D0 + DC
#define JD      3072      // 2*din
#define NE      64        // experts
#define BM      64        // tokens per block
#define BJ      64        // h-columns per chunk
#define KC      32        // k-chunk for GEMM1 staging
#define NTHREADS 256
#define PAD     4
#define EPSV    1e-9f

__global__ __launch_bounds__(NTHREADS, 2)
void router_fused(const float* __restrict__ inp,
                  const float* __restrict__ cnd,
                  const float* __restrict__ W1,
                  const float* __restrict__ W2,
                  float* __restrict__ out_mask,
                  float* __restrict__ out_topi,
                  float* __restrict__ out_rp,
                  float* __restrict__ out_probs)
{
    __shared__ float As[KC][BM + PAD];     // x tile, transposed [k][token]
    __shared__ float Bs[KC][BJ + PAD];     // W1 tile, transposed [k][j]
    __shared__ float Hs[BJ][BM + PAD];     // gelu(h) tile, transposed [j][token]; reused as logits[token][e]
    __shared__ float W2s[BJ][NE + PAD];    // W2 chunk, transposed [j][e]
    __shared__ int   i1s[BM], i2s[BM];
    __shared__ float rp1s[BM], rp2s[BM];

    const int tid = threadIdx.x;
    const int ty  = tid >> 4;   // 0..15 -> token group
    const int tx  = tid & 15;   // 0..15 -> col group
    const int t0  = blockIdx.x * BM;

    float lacc[4][4];
    #pragma unroll
    for (int i = 0; i < 4; ++i)
        #pragma unroll
        for (int j = 0; j < 4; ++j) lacc[i][j] = 0.f;

    for (int jc = 0; jc < JD; jc += BJ) {
        float hacc[4][4];
        #pragma unroll
        for (int i = 0; i < 4; ++i)
            #pragma unroll
            for (int j = 0; j < 4; ++j) hacc[i][j] = 0.f;

        for (int kc = 0; kc < DIN; kc += KC) {
            // stage x tile: 64 rows x 32 k = 512 float4 -> 2 per thread
            #pragma unroll
            for (int l = 0; l < 2; ++l) {
                int idx  = tid + l * NTHREADS;
                int row  = idx >> 3;           // token within tile
                int kk4  = (idx & 7) << 2;     // k within chunk (x4)
                int k    = kc + kk4;
                const float* src = (k < D0)
                    ? (inp + (size_t)(t0 + row) * D0 + k)
                    : (cnd + (size_t)(t0 + row) * DC + (k - D0));
                float4 v = *(const float4*)src;
                As[kk4 + 0][row] = v.x;
                As[kk4 + 1][row] = v.y;
                As[kk4 + 2][row] = v.z;
                As[kk4 + 3][row] = v.w;
            }
            // stage W1 tile (rows jc..jc+63, k chunk)
            #pragma unroll
            for (int l = 0; l < 2; ++l) {
                int idx = tid + l * NTHREADS;
                int row = idx >> 3;            // jj
                int kk4 = (idx & 7) << 2;
                float4 v = *(const float4*)(W1 + (size_t)(jc + row) * DIN + kc + kk4);
                Bs[kk4 + 0][row] = v.x;
                Bs[kk4 + 1][row] = v.y;
                Bs[kk4 + 2][row] = v.z;
                Bs[kk4 + 3][row] = v.w;
            }
            __syncthreads();
            #pragma unroll
            for (int kk = 0; kk < KC; ++kk) {
                float4 a = *(const float4*)&As[kk][ty << 2];
                float4 b = *(const float4*)&Bs[kk][tx << 2];
                float ar[4] = {a.x, a.y, a.z, a.w};
                float br[4] = {b.x, b.y, b.z, b.w};
                #pragma unroll
                for (int i = 0; i < 4; ++i)
                    #pragma unroll
                    for (int j = 0; j < 4; ++j)
                        hacc[i][j] = fmaf(ar[i], br[j], hacc[i][j]);
            }
            __syncthreads();
        }

        // exact GELU, store transposed into Hs[j][token]
        #pragma unroll
        for (int i = 0; i < 4; ++i)
            #pragma unroll
            for (int j = 0; j < 4; ++j) {
                float v = hacc[i][j];
                float g = 0.5f * v * (1.0f + erff(v * 0.70710678118654752f));
                Hs[(tx << 2) + j][(ty << 2) + i] = g;
            }

        // stage W2 chunk: W2s[jj][e] = W2[e][jc+jj]; 64x64 floats -> 4 float4/thread
        #pragma unroll
        for (int l = 0; l < 4; ++l) {
            int idx = tid + l * NTHREADS;
            int e   = idx >> 4;
            int jj4 = (idx & 15) << 2;
            float4 v = *(const float4*)(W2 + (size_t)e * JD + jc + jj4);
            W2s[jj4 + 0][e] = v.x;
            W2s[jj4 + 1][e] = v.y;
            W2s[jj4 + 2][e] = v.z;
            W2s[jj4 + 3][e] = v.w;
        }
        __syncthreads();

        // logits[token][e] += gelu_h[token][jj] * W2[e][jc+jj]
        #pragma unroll 8
        for (int jj = 0; jj < BJ; ++jj) {
            float4 h = *(const float4*)&Hs[jj][ty << 2];
            float4 w = *(const float4*)&W2s[jj][tx << 2];
            float hr[4] = {h.x, h.y, h.z, h.w};
            float wr[4] = {w.x, w.y, w.z, w.w};
            #pragma unroll
            for (int i = 0; i < 4; ++i)
                #pragma unroll
                for (int j = 0; j < 4; ++j)
                    lacc[i][j] = fmaf(hr[i], wr[j], lacc[i][j]);
        }
        __syncthreads();
    }

    // dump logits into Hs reused as ls[token][e] (row stride BM+PAD=68, 16B aligned)
    #pragma unroll
    for (int i = 0; i < 4; ++i) {
        float4 v = make_float4(lacc[i][0], lacc[i][1], lacc[i][2], lacc[i][3]);
        *(float4*)&Hs[(ty << 2) + i][tx << 2] = v;
    }
    __syncthreads();

    // per-token softmax + top-2 (threads 0..63, one token each)
    if (tid < BM) {
        float m = -3.402823466e38f;
        for (int e = 0; e < NE; ++e) m = fmaxf(m, Hs[tid][e]);
        float s = 0.f;
        for (int e = 0; e < NE; ++e) s += expf(Hs[tid][e] - m);
        float inv = 1.0f / s;
        float v1 = -1.f, v2 = -1.f;
        int   i1 = 0,    i2 = 0;
        for (int e = 0; e < NE; ++e) {
            float p = expf(Hs[tid][e] - m) * inv + EPSV;   // softmax + EPS
            p = fminf(p, 1.0f - EPSV);                     // clip upper (lower is implied)
            Hs[tid][e] = p;
            if (p > v1)      { v2 = v1; i2 = i1; v1 = p; i1 = e; }
            else if (p > v2) { v2 = p; i2 = e; }
        }
        i1s[tid] = i1; i2s[tid] = i2;
        float den = v1 + v2;
        rp1s[tid] = v1 / den;
        rp2s[tid] = v2 / den;
    }
    __syncthreads();

    // coalesced output writes
    for (int idx = tid; idx < BM * NE; idx += NTHREADS) {
        int r = idx >> 6;
        int e = idx & 63;
        size_t o = (size_t)(t0 + r) * NE + e;
        float p = Hs[r][e];
        int b1 = (e == i1s[r]);
        int b2 = (e == i2s[r]);
        out_probs[o] = p;
        out_mask[o]  = (b1 || b2) ? 1.0f : 0.0f;
        out_rp[o]    = b1 ? rp1s[r] : (b2 ? rp2s[r] : 0.0f);
    }
    if (tid < BM * 2) {
        int r = tid >> 1;
        int w = tid & 1;
        out_topi[(size_t)(t0 + r) * 2 + w] = (float)(w ? i2s[r] : i1s[r]);
    }
}

extern "C" void kernel_launch(void* const* d_in, const int* in_sizes, int n_in,
                              void* d_out, int out_size, void* d_ws, size_t ws_size,
                              hipStream_t stream) {
    const float* inp = (const float*)d_in[0];
    const float* cnd = (const float*)d_in[1];
    const float* W1  = (const float*)d_in[2];
    const float* W2  = (const float*)d_in[3];

    float* out = (float*)d_out;
    const size_t NT = (size_t)N_TOK;
    float* out_mask  = out;                                  // [N,64]
    float* out_topi  = out + NT * NE;                        // [N,2]
    float* out_rp    = out + NT * NE + NT * 2;               // [N,64]
    float* out_probs = out + NT * NE + NT * 2 + NT * NE;     // [N,64]

    dim3 grid(N_TOK / BM);   // 512 blocks
    dim3 block(NTHREADS);
    hipLaunchKernelGGL(router_fused, grid, block, 0, stream,
                       inp, cnd, W1, W2, out_mask, out_topi, out_rp, out_probs);
}

// Round 2
// 1620.858 us; speedup vs baseline: 3.5198x; 3.5198x over previous
//
#include <hip/hip_runtime.h>
#include <cmath>

// RouterCond fused: concat(x,cond)[32768x1536] @ W1^T[1536x3072] -> GELU ->
// @ W2^T[3072x64] -> softmax -> top2 outputs.
// Round 2: MFMA f16x2-split GEMMs (3 MFMAs emulate ~fp32 product precision).
#define N_TOK 32768
#define D0    1024
#define DCC   512
#define DIN   1536
#define JD    3072
#define NE    64
#define BM    128          // tokens per block
#define BJ    128          // j-chunk
#define KC    32           // k-step for GEMM1 staging
#define NJC   (JD/BJ)      // 24
#define NKS   (DIN/KC)     // 48
#define NTH   512
#define HLD   136          // H/W2t row stride in halves (136*2B=272B == 4 dwords mod 32 banks -> 2-way, free)
#define EPSV  1e-9f

typedef _Float16 half8 __attribute__((ext_vector_type(8)));
typedef float    f32x4 __attribute__((ext_vector_type(4)));

// LDS byte offsets (total 137216 <= 160 KiB, 1 block/CU)
#define OFF_A1H 0
#define OFF_A1L (OFF_A1H + BM*KC*2)     // 8192
#define OFF_B1H (OFF_A1L + BM*KC*2)     // 16384
#define OFF_B1L (OFF_B1H + BJ*KC*2)     // 24576
#define OFF_HH  (OFF_B1L + BJ*KC*2)     // 32768
#define OFF_HL  (OFF_HH  + BM*HLD*2)    // 67584
#define OFF_W2H (OFF_HL  + BM*HLD*2)    // 102400
#define OFF_W2L (OFF_W2H + NE*HLD*2)    // 119808
#define LDS_TOTAL (OFF_W2L + NE*HLD*2)  // 137216
// epilogue aliases (H region is dead after last GEMM2)
#define OFF_LRED OFF_HH                 // [128][68] f32 = 34816 B
#define OFF_EPI  (OFF_LRED + BM*68*4)   // 6 arrays x 128 x 4B

__device__ __forceinline__ f32x4 mfma16(half8 a, half8 b, f32x4 c) {
    return __builtin_amdgcn_mfma_f32_16x16x32_f16(a, b, c, 0, 0, 0);
}

// fp32 -> (hi fp16, lo fp16) split: x = hi + lo + O(2^-22 |x|)
__device__ __forceinline__ void split8(const float4 v0, const float4 v1, half8& hh, half8& hl) {
    float f[8] = {v0.x, v0.y, v0.z, v0.w, v1.x, v1.y, v1.z, v1.w};
    #pragma unroll
    for (int i = 0; i < 8; ++i) {
        _Float16 h = (_Float16)f[i];
        hh[i] = h;
        hl[i] = (_Float16)(f[i] - (float)h);
    }
}

__global__ __launch_bounds__(NTH, 2)
void router_mfma(const float* __restrict__ inp, const float* __restrict__ cnd,
                 const float* __restrict__ W1, const float* __restrict__ W2,
                 float* __restrict__ out_mask, float* __restrict__ out_topi,
                 float* __restrict__ out_rp, float* __restrict__ out_probs)
{
    __shared__ __align__(16) char smem[LDS_TOTAL];
    _Float16* const A1h = (_Float16*)(smem + OFF_A1H);
    _Float16* const A1l = (_Float16*)(smem + OFF_A1L);
    _Float16* const B1h = (_Float16*)(smem + OFF_B1H);
    _Float16* const B1l = (_Float16*)(smem + OFF_B1L);
    _Float16* const Hh  = (_Float16*)(smem + OFF_HH);
    _Float16* const Hl  = (_Float16*)(smem + OFF_HL);
    _Float16* const W2h = (_Float16*)(smem + OFF_W2H);
    _Float16* const W2l = (_Float16*)(smem + OFF_W2L);

    const int tid  = threadIdx.x;
    const int lane = tid & 63;
    const int w    = tid >> 6;     // wave 0..7
    const int tg   = w >> 1;       // token group: rows tg*32..+31
    const int jg   = w & 1;        // j half: cols jg*64..+63
    const int l15  = lane & 15;
    const int lg   = lane >> 4;    // 0..3
    const int lk8  = lg * 8;
    const int t0   = blockIdx.x * BM;

    // staging: thread -> (row, 8-float k chunk); b128 LDS writes, 8-phase optimal
    const int srow = tid >> 2;          // 0..127
    const int sk8  = (tid & 3) * 8;     // 0,8,16,24
    const int soff = srow * KC + sk8;

    // W2t staging: thread -> (expert, 16-float j chunk)
    const int we   = tid >> 3;          // 0..63
    const int wj16 = (tid & 7) * 16;

    const f32x4 vzero = {0.f, 0.f, 0.f, 0.f};
    f32x4 lacc[2][4];
    #pragma unroll
    for (int tf = 0; tf < 2; ++tf)
        #pragma unroll
        for (int ef = 0; ef < 4; ++ef) lacc[tf][ef] = vzero;

    // MFMA fragment LDS offsets (A: row=lane&15, k=(lane>>4)*8+b ; B: col=lane&15, same k)
    int aoff[2], boff[4], a2base[2], b2base[4];
    #pragma unroll
    for (int tf = 0; tf < 2; ++tf) {
        aoff[tf]   = (tg*32 + tf*16 + l15) * KC + lk8;
        a2base[tf] = (tg*32 + tf*16 + l15) * HLD;
    }
    #pragma unroll
    for (int jf = 0; jf < 4; ++jf) boff[jf] = (jg*64 + jf*16 + l15) * KC + lk8;
    #pragma unroll
    for (int ef = 0; ef < 4; ++ef) b2base[ef] = (ef*16 + l15) * HLD;

    const float* const xrowA = inp + (size_t)(t0 + srow) * D0;
    const float* const xrowC = cnd + (size_t)(t0 + srow) * DCC;

    for (int jc = 0; jc < NJC; ++jc) {
        const int bj0 = jc * BJ;
        const float* const w1row = W1 + (size_t)(bj0 + srow) * DIN;

        // prologue: load+stage k-step 0 (kc=0 is always on the inp side)
        float4 ra0 = *(const float4*)(xrowA + sk8);
        float4 ra1 = *(const float4*)(xrowA + sk8 + 4);
        float4 rb0 = *(const float4*)(w1row + sk8);
        float4 rb1 = *(const float4*)(w1row + sk8 + 4);
        {
            half8 hh, hl;
            split8(ra0, ra1, hh, hl);
            *(half8*)(A1h + soff) = hh; *(half8*)(A1l + soff) = hl;
            split8(rb0, rb1, hh, hl);
            *(half8*)(B1h + soff) = hh; *(half8*)(B1l + soff) = hl;
        }
        f32x4 acc1[2][4];
        #pragma unroll
        for (int tf = 0; tf < 2; ++tf)
            #pragma unroll
            for (int jf = 0; jf < 4; ++jf) acc1[tf][jf] = vzero;
        __syncthreads();

        for (int ks = 0; ks < NKS; ++ks) {
            if (ks + 1 < NKS) {               // prefetch next k-step into regs
                const int k = (ks + 1) * KC + sk8;
                const float* srcA = (k < D0) ? (xrowA + k) : (xrowC + (k - D0));
                ra0 = *(const float4*)srcA;
                ra1 = *(const float4*)(srcA + 4);
                rb0 = *(const float4*)(w1row + k);
                rb1 = *(const float4*)(w1row + k + 4);
            }
            half8 ah[2], al[2], bh[4], bl[4];
            #pragma unroll
            for (int tf = 0; tf < 2; ++tf) {
                ah[tf] = *(const half8*)(A1h + aoff[tf]);
                al[tf] = *(const half8*)(A1l + aoff[tf]);
            }
            #pragma unroll
            for (int jf = 0; jf < 4; ++jf) {
                bh[jf] = *(const half8*)(B1h + boff[jf]);
                bl[jf] = *(const half8*)(B1l + boff[jf]);
            }
            #pragma unroll
            for (int tf = 0; tf < 2; ++tf)
                #pragma unroll
                for (int jf = 0; jf < 4; ++jf) {
                    acc1[tf][jf] = mfma16(ah[tf], bh[jf], acc1[tf][jf]);
                    acc1[tf][jf] = mfma16(ah[tf], bl[jf], acc1[tf][jf]);
                    acc1[tf][jf] = mfma16(al[tf], bh[jf], acc1[tf][jf]);
                }
            __syncthreads();                  // all frag reads done
            if (ks + 1 < NKS) {
                half8 hh, hl;
                split8(ra0, ra1, hh, hl);
                *(half8*)(A1h + soff) = hh; *(half8*)(A1l + soff) = hl;
                split8(rb0, rb1, hh, hl);
                *(half8*)(B1h + soff) = hh; *(half8*)(B1l + soff) = hl;
                __syncthreads();              // writes visible
            }
        }

        // exact GELU + fp16x2 split -> H planes
        #pragma unroll
        for (int tf = 0; tf < 2; ++tf)
            #pragma unroll
            for (int jf = 0; jf < 4; ++jf)
                #pragma unroll
                for (int r = 0; r < 4; ++r) {
                    float v = acc1[tf][jf][r];
                    float g = 0.5f * v * (1.0f + erff(v * 0.70710678118654752f));
                    _Float16 ghi = (_Float16)g;
                    _Float16 glo = (_Float16)(g - (float)ghi);
                    const int o = (tg*32 + tf*16 + lg*4 + r) * HLD + (jg*64 + jf*16 + l15);
                    Hh[o] = ghi; Hl[o] = glo;
                }
        // stage W2t chunk (transposed to [e][j], split)
        {
            const float* src = W2 + (size_t)we * JD + bj0 + wj16;
            float4 q0 = *(const float4*)src;
            float4 q1 = *(const float4*)(src + 4);
            float4 q2 = *(const float4*)(src + 8);
            float4 q3 = *(const float4*)(src + 12);
            half8 hh, hl;
            const int o = we * HLD + wj16;
            split8(q0, q1, hh, hl);
            *(half8*)(W2h + o) = hh;     *(half8*)(W2l + o) = hl;
            split8(q2, q3, hh, hl);
            *(half8*)(W2h + o + 8) = hh; *(half8*)(W2l + o + 8) = hl;
        }
        __syncthreads();

        // GEMM2: logits += gelu_h @ W2^T over this wave's j-half
        #pragma unroll
        for (int ks2 = 0; ks2 < 2; ++ks2) {
            const int j2 = jg*64 + ks2*32 + lk8;
            half8 a2h[2], a2l[2];
            #pragma unroll
            for (int tf = 0; tf < 2; ++tf) {
                a2h[tf] = *(const half8*)(Hh + a2base[tf] + j2);
                a2l[tf] = *(const half8*)(Hl + a2base[tf] + j2);
            }
            #pragma unroll
            for (int ef = 0; ef < 4; ++ef) {
                half8 b2h = *(const half8*)(W2h + b2base[ef] + j2);
                half8 b2l = *(const half8*)(W2l + b2base[ef] + j2);
                #pragma unroll
                for (int tf = 0; tf < 2; ++tf) {
                    lacc[tf][ef] = mfma16(a2h[tf], b2h, lacc[tf][ef]);
                    lacc[tf][ef] = mfma16(a2h[tf], b2l, lacc[tf][ef]);
                    lacc[tf][ef] = mfma16(a2l[tf], b2h, lacc[tf][ef]);
                }
            }
        }
        __syncthreads();   // H/W2t/A1/B1 free for next jc
    }

    // ---- epilogue: reduce jg halves, softmax + top-2, write outputs
    float* const Lred = (float*)(smem + OFF_LRED);
    if (jg == 1) {
        #pragma unroll
        for (int tf = 0; tf < 2; ++tf)
            #pragma unroll
            for (int ef = 0; ef < 4; ++ef)
                #pragma unroll
                for (int r = 0; r < 4; ++r)
                    Lred[(tg*32 + tf*16 + lg*4 + r) * 68 + ef*16 + l15] = lacc[tf][ef][r];
    }
    __syncthreads();
    if (jg == 0) {
        #pragma unroll
        for (int tf = 0; tf < 2; ++tf)
            #pragma unroll
            for (int ef = 0; ef < 4; ++ef)
                #pragma unroll
                for (int r = 0; r < 4; ++r) {
                    const int o = (tg*32 + tf*16 + lg*4 + r) * 68 + ef*16 + l15;
                    Lred[o] += lacc[tf][ef][r];
                }
    }
    __syncthreads();

    float* const mA   = (float*)(smem + OFF_EPI);
    float* const invA = mA + BM;
    int*   const i1A  = (int*)(invA + BM);
    int*   const i2A  = i1A + BM;
    float* const rp1A = (float*)(i2A + BM);
    float* const rp2A = rp1A + BM;

    if (tid < BM) {
        const float* row = Lred + tid * 68;
        float m = -3.402823466e38f;
        for (int e = 0; e < NE; ++e) m = fmaxf(m, row[e]);
        float s = 0.f, v1 = -3.402823466e38f, v2 = -3.402823466e38f;
        int i1 = 0, i2 = 0;
        for (int e = 0; e < NE; ++e) {
            const float v = row[e];
            s += expf(v - m);
            if (v > v1)      { v2 = v1; i2 = i1; v1 = v; i1 = e; }
            else if (v > v2) { v2 = v; i2 = e; }
        }
        const float inv = 1.f / s;
        const float p1 = fminf(expf(v1 - m) * inv + EPSV, 1.f - EPSV);
        const float p2 = fminf(expf(v2 - m) * inv + EPSV, 1.f - EPSV);
        mA[tid] = m; invA[tid] = inv; i1A[tid] = i1; i2A[tid] = i2;
        const float den = p1 + p2;
        rp1A[tid] = p1 / den; rp2A[tid] = p2 / den;
    }
    __syncthreads();

    for (int idx = tid; idx < BM * NE; idx += NTH) {
        const int r = idx >> 6, e = idx & 63;
        const size_t o = (size_t)(t0 + r) * NE + e;
        const float p = fminf(expf(Lred[r * 68 + e] - mA[r]) * invA[r] + EPSV, 1.f - EPSV);
        const int b1 = (e == i1A[r]), b2 = (e == i2A[r]);
        out_probs[o] = p;
        out_mask[o]  = (b1 | b2) ? 1.f : 0.f;
        out_rp[o]    = b1 ? rp1A[r] : (b2 ? rp2A[r] : 0.f);
    }
    if (tid < BM * 2) {
        const int r = tid >> 1, q = tid & 1;
        out_topi[(size_t)(t0 + r) * 2 + q] = (float)(q ? i2A[r] : i1A[r]);
    }
}

extern "C" void kernel_launch(void* const* d_in, const int* in_sizes, int n_in,
                              void* d_out, int out_size, void* d_ws, size_t ws_size,
                              hipStream_t stream) {
    const float* inp = (const float*)d_in[0];
    const float* cnd = (const float*)d_in[1];
    const float* W1  = (const float*)d_in[2];
    const float* W2  = (const float*)d_in[3];

    float* out = (float*)d_out;
    const size_t NT = (size_t)N_TOK;
    float* out_mask  = out;
    float* out_topi  = out + NT * NE;
    float* out_rp    = out + NT * NE + NT * 2;
    float* out_probs = out + NT * NE + NT * 2 + NT * NE;

    dim3 grid(N_TOK / BM);   // 256 blocks -> 1 per CU
    dim3 block(NTH);
    hipLaunchKernelGGL(router_mfma, grid, block, 0, stream,
                       inp, cnd, W1, W2, out_mask, out_topi, out_rp, out_probs);
}